// Round 6
// baseline (287.499 us; speedup 1.0000x reference)
//
#include <hip/hip_runtime.h>
#include <math.h>

#define F 128

typedef __bf16 bf16_t;
typedef unsigned long long u64;
typedef __attribute__((ext_vector_type(8))) bf16_t bf16x8;
typedef __attribute__((ext_vector_type(2))) bf16_t bf16x2;
typedef __attribute__((ext_vector_type(4))) float floatx4;

#define DEG_SCALE 8388608.0f       // 2^23 fixed-point for weighted degree
#define DEG_INV   (1.0f / 8388608.0f)
#define NRM_SCALE 32768.0f         // 2^15 fixed-point for edge norm (norm < 0.708)
#define NRM_INV   (1.0f / 32768.0f)

// ---------------- spectral norm + Wt build (fused, one block) ----------------
__global__ __launch_bounds__(128) void spectral_wt_k(const float* __restrict__ W,
                                                     const float* __restrict__ u,
                                                     bf16_t* __restrict__ Wt) {
    __shared__ float sv[F];
    __shared__ float red[F];
    __shared__ float snorm;
    __shared__ float s_is;
    int t = threadIdx.x;  // 128 threads
    float s = 0.f;
    for (int i = 0; i < F; ++i) s += W[i * F + t] * u[i];
    red[t] = s * s;
    __syncthreads();
    if (t == 0) {
        float a = 0.f;
        for (int i = 0; i < F; ++i) a += red[i];
        snorm = sqrtf(a);
    }
    __syncthreads();
    sv[t] = s / (snorm + 1e-12f);  // v
    __syncthreads();
    float s2 = 0.f;
    for (int j = 0; j < F; ++j) s2 += W[t * F + j] * sv[j];
    red[t] = s2 * s2;
    __syncthreads();
    if (t == 0) {
        float a = 0.f;
        for (int i = 0; i < F; ++i) a += red[i];
        float nt = sqrtf(a);
        float sigma = a / (nt + 1e-12f);
        s_is = 1.0f / sigma;
    }
    __syncthreads();
    float is = s_is;
    for (int nrow = 0; nrow < F; ++nrow)
        Wt[nrow * F + t] = (bf16_t)(W[t * F + nrow] * is);
}

// ---------------- init packed degree/count to 0 ----------------
__global__ __launch_bounds__(256) void init_k(u64* __restrict__ dc, int n) {
    int i = blockIdx.x * 256 + threadIdx.x;
    if (i < n) dc[i] = 0ULL;
}

// ---------------- fused: per-edge packed atomic + fp32->bf16 conv ----------------
__global__ __launch_bounds__(256) void count_conv_k(const int* __restrict__ col,
                                                    const float* __restrict__ wt,
                                                    u64* __restrict__ dc, int e_cnt,
                                                    const float* __restrict__ x,
                                                    bf16_t* __restrict__ xh, int total8,
                                                    int gCount) {
    int b = blockIdx.x;
    if (b < gCount) {
        int e = b * 256 + threadIdx.x;
        if (e < e_cnt) {
            int c = col[e];
            float w = 1.0f / (1.0f + expf(-wt[e]));  // sigmoid
            u64 pkt = (1ULL << 32) | (u64)(unsigned)rintf(w * DEG_SCALE);
            atomicAdd(dc + c, pkt);
        }
    } else {
        int i = (b - gCount) * 256 + threadIdx.x;  // 8 elems per thread
        if (i < total8) {
            const float4* p = (const float4*)x + (size_t)i * 2;
            float4 a = p[0], bb = p[1];
            bf16x8 v;
            v[0] = (bf16_t)a.x;  v[1] = (bf16_t)a.y;  v[2] = (bf16_t)a.z;  v[3] = (bf16_t)a.w;
            v[4] = (bf16_t)bb.x; v[5] = (bf16_t)bb.y; v[6] = (bf16_t)bb.z; v[7] = (bf16_t)bb.w;
            *(bf16x8*)(xh + (size_t)i * 8) = v;
        }
    }
}

// ---------------- scan pass 1 (block sums of cnt) + fused dinv ----------------
#define STILE 1024
__global__ __launch_bounds__(256) void scan1_k(const u64* __restrict__ dc,
                                               int* __restrict__ bsum,
                                               float* __restrict__ dinv, int n) {
    __shared__ int red[256];
    int t = threadIdx.x;
    int base = blockIdx.x * STILE + t * 4;
    int s = 0;
    for (int i = 0; i < 4; ++i) {
        if (base + i < n) {
            u64 v = dc[base + i];
            s += (int)(v >> 32);
            float d = 1.0f + (float)(unsigned)(v & 0xFFFFFFFFULL) * DEG_INV;
            dinv[base + i] = 1.0f / sqrtf(d);  // d >= 1 always (self loop)
        }
    }
    red[t] = s;
    __syncthreads();
    for (int o = 128; o > 0; o >>= 1) { if (t < o) red[t] += red[t + o]; __syncthreads(); }
    if (t == 0) bsum[blockIdx.x] = red[0];
}

__global__ void scan2_k(int* __restrict__ bsum, int g, int* __restrict__ offsets, int n) {
    if (threadIdx.x == 0 && blockIdx.x == 0) {
        int acc = 0;
        for (int i = 0; i < g; ++i) { int v = bsum[i]; bsum[i] = acc; acc += v; }
        offsets[n] = acc;  // == E
    }
}

__global__ __launch_bounds__(256) void scan3_k(const u64* __restrict__ dc,
                                               const int* __restrict__ bsum,
                                               int* __restrict__ offsets,
                                               int* __restrict__ cursor, int n) {
    __shared__ int sc[256];
    int t = threadIdx.x;
    int base = blockIdx.x * STILE + t * 4;
    int v[4] = {0, 0, 0, 0};
    for (int i = 0; i < 4; ++i)
        if (base + i < n) v[i] = (int)(dc[base + i] >> 32);
    int ts = v[0] + v[1] + v[2] + v[3];
    sc[t] = ts;
    __syncthreads();
    for (int o = 1; o < 256; o <<= 1) {
        int val = sc[t];
        int add = (t >= o) ? sc[t - o] : 0;
        __syncthreads();
        sc[t] = val + add;
        __syncthreads();
    }
    int run = bsum[blockIdx.x] + sc[t] - ts;  // exclusive base for this thread
    for (int i = 0; i < 4; ++i) {
        if (base + i < n) { offsets[base + i] = run; cursor[base + i] = run; }
        run += v[i];
    }
}

// ---------------- counting-sort fill: packed u32 (src<<15 | norm_q15) ----------------
__global__ __launch_bounds__(256) void fill_k(const int* __restrict__ row,
                                              const int* __restrict__ col,
                                              const float* __restrict__ wt,
                                              const float* __restrict__ dinv,
                                              int* __restrict__ cursor,
                                              unsigned* __restrict__ edat, int e_cnt) {
    int e = blockIdx.x * 256 + threadIdx.x;
    if (e < e_cnt) {
        int r = row[e], c = col[e];
        float w = 1.0f / (1.0f + expf(-wt[e]));
        float nv = dinv[r] * w * dinv[c];       // < w/sqrt(1+w) < 0.708
        unsigned q = (unsigned)(nv * NRM_SCALE + 0.5f);  // <= 23171, fits 15 bits
        int p = atomicAdd(cursor + c, 1);
        edat[p] = ((unsigned)r << 15) | q;
    }
}

// ---------------- fused gather + MFMA GEMM, barrier-free per-wave ----------------
// Each wave: gather 16 nodes -> own 16x136 bf16 LDS tile -> 16x128 @ 128x128 MFMA
// (B-frags straight from global Wt, L1/L2-hot) -> epilogue store to out.
#define LDK 136  // 128 + 8 pad
template <int USE_BF16>
__global__ __launch_bounds__(256) void gather_gemm_t(const int* __restrict__ offsets,
                                                     const unsigned* __restrict__ edat,
                                                     const float* __restrict__ dinv,
                                                     const float* __restrict__ x,
                                                     const bf16_t* __restrict__ xh,
                                                     const bf16_t* __restrict__ Wt,
                                                     const float* __restrict__ bias,
                                                     float* __restrict__ out, int n) {
    __shared__ bf16_t As[4 * 16 * LDK];
    int wave = threadIdx.x >> 6, lane = threadIdx.x & 63;
    bf16_t* myAs = As + wave * 16 * LDK;
    int nodeBase = blockIdx.x * 64 + wave * 16;
    const float2* x2 = (const float2*)x;

    // ---- gather phase: 16 nodes, one at a time, whole wave per node ----
    for (int i = 0; i < 16; ++i) {
        int node = nodeBase + i;
        float2 cacc = make_float2(0.f, 0.f);
        if (node < n) {
            float dv = dinv[node];
            float2 xv = x2[(size_t)node * 64 + lane];
            cacc.x = dv * dv * xv.x;  // self loop
            cacc.y = dv * dv * xv.y;
            int s = offsets[node], e = offsets[node + 1];
            for (int b = s; b < e; b += 64) {
                int cnt = min(64, e - b);
                unsigned ed = 0;
                if (lane < cnt) ed = edat[b + lane];
                int j = 0;
                for (; j + 4 <= cnt; j += 4) {
                    unsigned e0 = __shfl(ed, j + 0), e1 = __shfl(ed, j + 1);
                    unsigned e2 = __shfl(ed, j + 2), e3 = __shfl(ed, j + 3);
                    int r0 = e0 >> 15, r1 = e1 >> 15, r2 = e2 >> 15, r3 = e3 >> 15;
                    float n0 = (float)(e0 & 32767u) * NRM_INV;
                    float n1 = (float)(e1 & 32767u) * NRM_INV;
                    float n2 = (float)(e2 & 32767u) * NRM_INV;
                    float n3 = (float)(e3 & 32767u) * NRM_INV;
                    if (USE_BF16) {
                        unsigned v0 = ((const unsigned*)(xh + (size_t)r0 * F))[lane];
                        unsigned v1 = ((const unsigned*)(xh + (size_t)r1 * F))[lane];
                        unsigned v2 = ((const unsigned*)(xh + (size_t)r2 * F))[lane];
                        unsigned v3 = ((const unsigned*)(xh + (size_t)r3 * F))[lane];
                        cacc.x = fmaf(n0, __uint_as_float(v0 << 16), cacc.x);
                        cacc.y = fmaf(n0, __uint_as_float(v0 & 0xFFFF0000u), cacc.y);
                        cacc.x = fmaf(n1, __uint_as_float(v1 << 16), cacc.x);
                        cacc.y = fmaf(n1, __uint_as_float(v1 & 0xFFFF0000u), cacc.y);
                        cacc.x = fmaf(n2, __uint_as_float(v2 << 16), cacc.x);
                        cacc.y = fmaf(n2, __uint_as_float(v2 & 0xFFFF0000u), cacc.y);
                        cacc.x = fmaf(n3, __uint_as_float(v3 << 16), cacc.x);
                        cacc.y = fmaf(n3, __uint_as_float(v3 & 0xFFFF0000u), cacc.y);
                    } else {
                        float2 a0 = x2[(size_t)r0 * 64 + lane];
                        float2 a1 = x2[(size_t)r1 * 64 + lane];
                        float2 a2 = x2[(size_t)r2 * 64 + lane];
                        float2 a3 = x2[(size_t)r3 * 64 + lane];
                        cacc.x = fmaf(n0, a0.x, cacc.x); cacc.y = fmaf(n0, a0.y, cacc.y);
                        cacc.x = fmaf(n1, a1.x, cacc.x); cacc.y = fmaf(n1, a1.y, cacc.y);
                        cacc.x = fmaf(n2, a2.x, cacc.x); cacc.y = fmaf(n2, a2.y, cacc.y);
                        cacc.x = fmaf(n3, a3.x, cacc.x); cacc.y = fmaf(n3, a3.y, cacc.y);
                    }
                }
                for (; j < cnt; ++j) {
                    unsigned ee = __shfl(ed, j);
                    int r = ee >> 15;
                    float nv = (float)(ee & 32767u) * NRM_INV;
                    if (USE_BF16) {
                        unsigned v = ((const unsigned*)(xh + (size_t)r * F))[lane];
                        cacc.x = fmaf(nv, __uint_as_float(v << 16), cacc.x);
                        cacc.y = fmaf(nv, __uint_as_float(v & 0xFFFF0000u), cacc.y);
                    } else {
                        float2 xr = x2[(size_t)r * 64 + lane];
                        cacc.x = fmaf(nv, xr.x, cacc.x);
                        cacc.y = fmaf(nv, xr.y, cacc.y);
                    }
                }
            }
        }
        bf16x2 v2w;
        v2w.x = (bf16_t)cacc.x;
        v2w.y = (bf16_t)cacc.y;
        *(bf16x2*)(myAs + i * LDK + lane * 2) = v2w;  // row i, cols lane*2..+1
    }

    // ---- MFMA phase: this wave's own 16 rows only (no barrier needed) ----
    int l16 = lane & 15, q = lane >> 4;
    floatx4 acc[8];
#pragma unroll
    for (int nt = 0; nt < 8; ++nt) acc[nt] = (floatx4){0.f, 0.f, 0.f, 0.f};

#pragma unroll
    for (int kt = 0; kt < 4; ++kt) {
        bf16x8 a = *(bf16x8*)(myAs + l16 * LDK + kt * 32 + q * 8);
#pragma unroll
        for (int nt = 0; nt < 8; ++nt) {
            bf16x8 b = *(const bf16x8*)(Wt + (nt * 16 + l16) * F + kt * 32 + q * 8);
            acc[nt] = __builtin_amdgcn_mfma_f32_16x16x32_bf16(a, b, acc[nt], 0, 0, 0);
        }
    }

    // epilogue: C/D layout col = lane&15, row = q*4 + reg
#pragma unroll
    for (int nt = 0; nt < 8; ++nt) {
        int colo = nt * 16 + l16;
        float bv = bias[colo];
#pragma unroll
        for (int r = 0; r < 4; ++r) {
            int grow = nodeBase + q * 4 + r;
            if (grow < n) out[(size_t)grow * F + colo] = acc[nt][r] + bv;
        }
    }
}

extern "C" void kernel_launch(void* const* d_in, const int* in_sizes, int n_in,
                              void* d_out, int out_size, void* d_ws, size_t ws_size,
                              hipStream_t stream) {
    const float* x    = (const float*)d_in[0];
    const int*   ei   = (const int*)d_in[1];
    const float* ewt  = (const float*)d_in[2];
    const float* W    = (const float*)d_in[3];
    const float* bias = (const float*)d_in[4];
    const float* u    = (const float*)d_in[5];
    float* out = (float*)d_out;

    int n_nodes = in_sizes[0] / F;
    int e_cnt   = in_sizes[2];
    const int* row = ei;
    const int* col = ei + e_cnt;

    // workspace layout
    char* wsb = (char*)d_ws;
    float* dinv    = (float*)wsb;                                   // N floats
    size_t off = ((size_t)n_nodes * 4 + 7) & ~(size_t)7;
    u64*   dc      = (u64*)(wsb + off);                             // N u64
    off += (size_t)n_nodes * 8;
    int*   offsets = (int*)(wsb + off);                             // N+1
    off += (size_t)(n_nodes + 1) * 4;
    int*   cursor  = (int*)(wsb + off);                             // N
    off += (size_t)n_nodes * 4;
    int*   bsum    = (int*)(wsb + off);                             // 128
    off += 128 * 4;
    off = (off + 15) & ~(size_t)15;
    unsigned* edat = (unsigned*)(wsb + off);                        // E u32 (packed)
    off += (size_t)e_cnt * 4;
    off = (off + 15) & ~(size_t)15;
    bf16_t* Wt     = (bf16_t*)(wsb + off);                          // 128x128 bf16
    off += (size_t)F * F * 2;
    bf16_t* xh     = (bf16_t*)(wsb + off);                          // N*128 bf16
    size_t need_bf16 = off + (size_t)n_nodes * F * 2;
    int use_bf16 = (ws_size >= need_bf16);

    int g_scan  = (n_nodes + STILE - 1) / STILE;
    int gCount  = (e_cnt + 255) / 256;
    int total8  = n_nodes * (F / 8);
    int gConv   = use_bf16 ? (total8 + 255) / 256 : 0;
    int gFused  = (n_nodes + 63) / 64;

    spectral_wt_k<<<1, 128, 0, stream>>>(W, u, Wt);
    init_k<<<(n_nodes + 255) / 256, 256, 0, stream>>>(dc, n_nodes);
    count_conv_k<<<gCount + gConv, 256, 0, stream>>>(col, ewt, dc, e_cnt, x, xh, total8, gCount);
    scan1_k<<<g_scan, 256, 0, stream>>>(dc, bsum, dinv, n_nodes);
    scan2_k<<<1, 64, 0, stream>>>(bsum, g_scan, offsets, n_nodes);
    scan3_k<<<g_scan, 256, 0, stream>>>(dc, bsum, offsets, cursor, n_nodes);
    fill_k<<<(e_cnt + 255) / 256, 256, 0, stream>>>(row, col, ewt, dinv, cursor, edat, e_cnt);
    if (use_bf16) {
        gather_gemm_t<1><<<gFused, 256, 0, stream>>>(offsets, edat, dinv, x, xh, Wt, bias, out, n_nodes);
    } else {
        gather_gemm_t<0><<<gFused, 256, 0, stream>>>(offsets, edat, dinv, x, xh, Wt, bias, out, n_nodes);
    }
}